// Round 7
// baseline (333.034 us; speedup 1.0000x reference)
//
#include <hip/hip_runtime.h>
#include <hip/hip_bf16.h>
#include <math.h>

// Problem constants
#define TT 1024
#define DIM 1024
#define HH 8
#define QLR 768
#define KVLR 512
#define DNOPE 128
#define DROPE 64
#define DV 128
#define DK 192            // DNOPE + DROPE
#define HDK (HH*DK)       // 1536
#define HKV (HH*(DNOPE+DV)) // 2048
#define NBODY (TT/16)     // 64

// Phase-A blob layout (floats) per (chunk n, head h):
#define OY   0            // after chunk_prep2: Ylam (y scaled by lam_{n-1})
#define OQ   3072         // after chunk_prep2: Qlam
#define OC   6144         // KcT [192][20] padded; slot 16 of each row = lam[d]
#define OPL  9984
#define OU   10240        // u' transposed: [128 cc][16 ti]
#define OLAM 12288
#define OGY  12480        // Gy = y_n . Kc_{n-1}  (16x16)
#define OGQ  12736        // Gq = q_n . Kc_{n-1}  (16x16)
#define PABLK 12992

typedef __attribute__((ext_vector_type(8))) short short8;
typedef __attribute__((ext_vector_type(4))) float f32x4;

// ---------------------------------------------------------------------------
// bf16 split helpers
// ---------------------------------------------------------------------------
__device__ __forceinline__ unsigned short f2bf_rn(float f) {
    unsigned u = __float_as_uint(f);
    unsigned lsb = (u >> 16) & 1u;
    u += 0x7fffu + lsb;
    return (unsigned short)(u >> 16);
}
__device__ __forceinline__ float bf2f(unsigned short h) {
    return __uint_as_float(((unsigned)h) << 16);
}

__device__ __forceinline__ void gl_lds16(const float* g, float* l) {
    __builtin_amdgcn_global_load_lds(
        (const __attribute__((address_space(1))) void*)g,
        (__attribute__((address_space(3))) void*)l, 16, 0, 0);
}
__device__ __forceinline__ void gl_lds16s(const unsigned short* g, unsigned short* l) {
    __builtin_amdgcn_global_load_lds(
        (const __attribute__((address_space(1))) void*)g,
        (__attribute__((address_space(3))) void*)l, 16, 0, 0);
}

// ---------------------------------------------------------------------------
// Weight transpose+split: W[K][N] f32 -> Wt_h[N][K], Wt_l[N][K] bf16.
// ---------------------------------------------------------------------------
__global__ __launch_bounds__(256) void wconv(
    const float* __restrict__ W0, unsigned short* __restrict__ H0,
    unsigned short* __restrict__ L0, int K0, int N0, int T0,
    const float* __restrict__ W1, unsigned short* __restrict__ H1,
    unsigned short* __restrict__ L1, int K1, int N1, int T1,
    const float* __restrict__ W2, unsigned short* __restrict__ H2,
    unsigned short* __restrict__ L2, int K2, int N2, int T2)
{
    __shared__ float Ls[64][65];
    int bx = blockIdx.x;
    const float* W; unsigned short* H; unsigned short* L; int K, N;
    if (bx < T0)           { W = W0; H = H0; L = L0; K = K0; N = N0; }
    else if (bx < T0 + T1) { bx -= T0; W = W1; H = H1; L = L1; K = K1; N = N1; }
    else                   { bx -= T0 + T1; W = W2; H = H2; L = L2; K = K2; N = N2; }

    const int NT = N >> 6;
    const int kt = bx / NT, nt = bx - kt * NT;
    const int k0 = kt * 64, n0 = nt * 64;
    const int tid = threadIdx.x;
    const int r = tid >> 2, c = (tid & 3) * 16;

#pragma unroll
    for (int i = 0; i < 4; i++)
        *(float4*)&Ls[r][c + i * 4] =
            *(const float4*)&W[(size_t)(k0 + r) * N + n0 + c + i * 4];
    __syncthreads();

    const int nr = tid >> 2, kc = (tid & 3) * 16;
    unsigned short hb[16], lb[16];
#pragma unroll
    for (int j = 0; j < 16; j++) {
        float v = Ls[kc + j][nr];
        unsigned short h = f2bf_rn(v);
        hb[j] = h;
        lb[j] = f2bf_rn(v - bf2f(h));
    }
    size_t ob = (size_t)(n0 + nr) * K + k0 + kc;
    *(float4*)&H[ob]     = ((float4*)hb)[0];
    *(float4*)&H[ob + 8] = ((float4*)hb)[1];
    *(float4*)&L[ob]     = ((float4*)lb)[0];
    *(float4*)&L[ob + 8] = ((float4*)lb)[1];
}

// ---------------------------------------------------------------------------
// Activation split: A f32 -> H, L bf16.
// ---------------------------------------------------------------------------
__global__ __launch_bounds__(256) void aconv(
    const float* __restrict__ A, unsigned short* __restrict__ H,
    unsigned short* __restrict__ L)
{
    int i = (blockIdx.x * 256 + threadIdx.x) * 8;
    float4 v0 = *(const float4*)&A[i];
    float4 v1 = *(const float4*)&A[i + 4];
    float vv[8] = {v0.x, v0.y, v0.z, v0.w, v1.x, v1.y, v1.z, v1.w};
    unsigned short hb[8], lb[8];
#pragma unroll
    for (int j = 0; j < 8; j++) {
        unsigned short h = f2bf_rn(vv[j]);
        hb[j] = h;
        lb[j] = f2bf_rn(vv[j] - bf2f(h));
    }
    *(float4*)&H[i] = *(float4*)hb;
    *(float4*)&L[i] = *(float4*)lb;
}

// ---------------------------------------------------------------------------
// bf16x3 MFMA GEMM — R22: R21's 128x64 gl_lds structure + DOUBLE-BUFFERED
// LDS with distance-1 prefetch (R21 regressed because it serialized the
// global latency into every K-step: stage was drained at the immediately
// following barrier). Schedule per K-step:
//   stage(buf^1, k+32)  ->  compute from buf  ->  vmcnt(0)+barrier
// so the drain waits on loads issued a full compute-phase (~24 MFMA +
// 12 ds_read) earlier. WAR-safe: buf^1's last readers passed the previous
// iteration's end barrier before this stage overwrites it. One barrier per
// K-step. Swizzle + fragment math byte-identical to R21 (verified passing).
// LDS 48KB -> 3 blocks/CU.
// ---------------------------------------------------------------------------
__global__ __launch_bounds__(256) void gemm_bt(
    const unsigned short* __restrict__ Ah0, const unsigned short* __restrict__ Al0,
    const unsigned short* __restrict__ Bh0, const unsigned short* __restrict__ Bl0,
    float* __restrict__ C0, int K0, int N0, int T0,
    const unsigned short* __restrict__ Ah1, const unsigned short* __restrict__ Al1,
    const unsigned short* __restrict__ Bh1, const unsigned short* __restrict__ Bl1,
    float* __restrict__ C1, int K1, int N1, int T1,
    const unsigned short* __restrict__ Ah2, const unsigned short* __restrict__ Al2,
    const unsigned short* __restrict__ Bh2, const unsigned short* __restrict__ Bl2,
    float* __restrict__ C2, int K2, int N2, int T2)
{
    __shared__ unsigned short Ahs[2][128 * 32], Als[2][128 * 32];
    __shared__ unsigned short Bhs[2][64 * 32],  Bls[2][64 * 32];

    int bx = blockIdx.x;
    const unsigned short *Ah, *Al, *Bh, *Bl; float* C; int K, N;
    if (bx < T0) {
        Ah = Ah0; Al = Al0; Bh = Bh0; Bl = Bl0; C = C0; K = K0; N = N0;
    } else if (bx < T0 + T1) {
        bx -= T0; Ah = Ah1; Al = Al1; Bh = Bh1; Bl = Bl1; C = C1; K = K1; N = N1;
    } else {
        bx -= T0 + T1; Ah = Ah2; Al = Al2; Bh = Bh2; Bl = Bl2; C = C2; K = K2; N = N2;
    }

    const int tid = threadIdx.x;
    const int w = tid >> 6, l = tid & 63;
    const int q = l >> 4, m16 = l & 15;
    const int bm = blockIdx.y * 128, bn = bx * 64;

    const int lr = l >> 2, lq = l & 3;   // staging: row-within-16, 16B slot

    f32x4 acc[2][4];
#pragma unroll
    for (int i = 0; i < 2; i++)
#pragma unroll
        for (int j = 0; j < 4; j++)
            acc[i][j] = (f32x4){0.f, 0.f, 0.f, 0.f};

    auto stage = [&](int buf, int k0) {
#pragma unroll
        for (int i = 0; i < 2; i++) {
            const int rbase = w * 32 + i * 16;
            const int row = rbase + lr;
            const int qq = lq ^ ((row >> 1) & 3);         // swizzled source
            const size_t go = (size_t)(bm + row) * K + k0 + qq * 8;
            gl_lds16s(Ah + go, &Ahs[buf][rbase * 32]);
            gl_lds16s(Al + go, &Als[buf][rbase * 32]);
        }
        {
            const int rbase = w * 16;
            const int row = rbase + lr;
            const int qq = lq ^ ((row >> 1) & 3);
            const size_t go = (size_t)(bn + row) * K + k0 + qq * 8;
            gl_lds16s(Bh + go, &Bhs[buf][rbase * 32]);
            gl_lds16s(Bl + go, &Bls[buf][rbase * 32]);
        }
    };

    auto compute = [&](int buf) {
        short8 fah[2], fal[2], fbh[4], fbl[4];
#pragma unroll
        for (int mt = 0; mt < 2; mt++) {
            const int row = w * 32 + mt * 16 + m16;
            const int qa = (q ^ ((row >> 1) & 3)) * 8;
            fah[mt] = *(const short8*)&Ahs[buf][row * 32 + qa];
            fal[mt] = *(const short8*)&Als[buf][row * 32 + qa];
        }
#pragma unroll
        for (int nt = 0; nt < 4; nt++) {
            const int row = nt * 16 + m16;
            const int qb = (q ^ ((row >> 1) & 3)) * 8;
            fbh[nt] = *(const short8*)&Bhs[buf][row * 32 + qb];
            fbl[nt] = *(const short8*)&Bls[buf][row * 32 + qb];
        }
#pragma unroll
        for (int mt = 0; mt < 2; mt++)
#pragma unroll
            for (int nt = 0; nt < 4; nt++) {
                acc[mt][nt] = __builtin_amdgcn_mfma_f32_16x16x32_bf16(
                    fah[mt], fbh[nt], acc[mt][nt], 0, 0, 0);
                acc[mt][nt] = __builtin_amdgcn_mfma_f32_16x16x32_bf16(
                    fah[mt], fbl[nt], acc[mt][nt], 0, 0, 0);
                acc[mt][nt] = __builtin_amdgcn_mfma_f32_16x16x32_bf16(
                    fal[mt], fbh[nt], acc[mt][nt], 0, 0, 0);
            }
    };

#define GBAR asm volatile("s_waitcnt vmcnt(0) lgkmcnt(0)\n\ts_barrier" ::: "memory")

    stage(0, 0);
    GBAR;                             // buf0 resident
    // K is a multiple of 64 for all three problems (1024 / 768 / 512).
    for (int k0 = 0; k0 < K; k0 += 64) {
        stage(1, k0 + 32);            // k0+32 < K always (k0 <= K-64)
        asm volatile("" ::: "memory");
        compute(0);
        GBAR;                         // buf1 resident; buf0 readers done
        if (k0 + 64 < K) stage(0, k0 + 64);
        asm volatile("" ::: "memory");
        compute(1);
        GBAR;                         // buf0 resident; buf1 readers done
    }
#undef GBAR

#pragma unroll
    for (int mt = 0; mt < 2; mt++)
#pragma unroll
        for (int nt = 0; nt < 4; nt++) {
            const int mrow = bm + w * 32 + mt * 16 + q * 4;
            const int ncol = bn + nt * 16 + m16;
#pragma unroll
            for (int r = 0; r < 4; r++)
                C[(size_t)(mrow + r) * N + ncol] = acc[mt][nt][r];
        }
}

// ---------------------------------------------------------------------------
// Fused RMSNorm (both norms in one launch; region-routed) -> bf16 hi/lo
// ---------------------------------------------------------------------------
__global__ __launch_bounds__(256) void rmsnorm_bf2(
    const float* __restrict__ in0, const float* __restrict__ w0,
    unsigned short* __restrict__ oh0, unsigned short* __restrict__ ol0,
    const float* __restrict__ in1, const float* __restrict__ w1,
    unsigned short* __restrict__ oh1, unsigned short* __restrict__ ol1)
{
    int bx = blockIdx.x;
    const float* in; const float* w; unsigned short *oh, *ol;
    int t, stride, ncols; float inv_n;
    if (bx < TT) {
        t = bx; in = in0; w = w0; oh = oh0; ol = ol0;
        stride = QLR; ncols = QLR; inv_n = 1.f / QLR;
    } else {
        t = bx - TT; in = in1; w = w1; oh = oh1; ol = ol1;
        stride = KVLR + DROPE; ncols = KVLR; inv_n = 1.f / KVLR;
    }
    const int tid = threadIdx.x;
    const float* row = in + (size_t)t * stride;
    float ss = 0.f;
    for (int c = tid; c < ncols; c += 256) { float v = row[c]; ss += v * v; }
#pragma unroll
    for (int m = 1; m < 64; m <<= 1) ss += __shfl_xor(ss, m);
    __shared__ float red[4];
    if ((tid & 63) == 0) red[tid >> 6] = ss;
    __syncthreads();
    float tot = red[0] + red[1] + red[2] + red[3];
    float scale = rsqrtf(tot * inv_n + 1e-5f);
    for (int c = tid; c < ncols; c += 256) {
        float v = row[c] * scale * w[c];
        unsigned short h = f2bf_rn(v);
        oh[(size_t)t * ncols + c] = h;
        ol[(size_t)t * ncols + c] = f2bf_rn(v - bf2f(h));
    }
}

// ---------------------------------------------------------------------------
// Fused small kernels: logsig_relayout [0,6144) + beta [6144,8192) +
// prep_qk [8192,10240). All block-range routed (wave-uniform).
// ---------------------------------------------------------------------------
__global__ __launch_bounds__(256) void small_fused(
    const float* __restrict__ g, const float* __restrict__ bias,
    float* __restrict__ la_h,
    const float* __restrict__ x, const float* __restrict__ wb,
    float* __restrict__ betab,
    const float* __restrict__ qraw, const float* __restrict__ kvb,
    const float* __restrict__ kv_all, float* __restrict__ q_h,
    float* __restrict__ k_h)
{
    int bx = blockIdx.x;
    if (bx < 6144) {
        int i = bx * 256 + threadIdx.x;   // < TT*HDK
        int t = i / HDK, col = i - t * HDK;
        int h = col / DK, d = col - h * DK;
        float z = g[i] + bias[col];
        float la = fminf(z, 0.f) - log1pf(__expf(-fabsf(z)));
        la_h[((size_t)h * TT + t) * DK + d] = la;
        return;
    }
    bx -= 6144;
    const int lane = threadIdx.x & 63, wv = threadIdx.x >> 6;
    if (bx < 2048) {
        const int p = bx * 4 + wv;        // p = t*8 + h
        const int t = p >> 3, h = p & 7;
        const float* xr = x + (size_t)t * DIM;
        float s = 0.f;
        for (int e = lane; e < DIM; e += 64) s += xr[e] * wb[e * HH + h];
#pragma unroll
        for (int m = 1; m < 64; m <<= 1) s += __shfl_xor(s, m);
        if (lane == 0) betab[p] = 1.f / (1.f + expf(-s));
        return;
    }
    bx -= 2048;
    {
        const int p = bx * 4 + wv;
        const int t = p >> 3, h = p & 7;

        const float* qrow = qraw + (size_t)t * HDK + h * DK;
        float q0 = qrow[lane], q1 = qrow[lane + 64], q2 = qrow[lane + 128];
        float ss = q0 * q0 + q1 * q1 + q2 * q2;
#pragma unroll
        for (int m = 1; m < 64; m <<= 1) ss += __shfl_xor(ss, m);
        float sc = rsqrtf(ss + 1e-6f) * 0.07216878364870323f;  // * DK^-0.5
        float* qo = q_h + ((size_t)h * TT + t) * DK;
        qo[lane] = q0 * sc; qo[lane + 64] = q1 * sc; qo[lane + 128] = q2 * sc;

        const float* knope = kvb + (size_t)t * HKV + h * (DNOPE + DV);
        float k0 = knope[lane], k1 = knope[lane + 64];
        float k2 = kv_all[(size_t)t * (KVLR + DROPE) + KVLR + lane];
        float ks = k0 * k0 + k1 * k1 + k2 * k2;
#pragma unroll
        for (int m = 1; m < 64; m <<= 1) ks += __shfl_xor(ks, m);
        float kc = rsqrtf(ks + 1e-6f);
        float* ko = k_h + ((size_t)h * TT + t) * DK;
        ko[lane] = k0 * kc; ko[lane + 64] = k1 * kc; ko[lane + 128] = k2 * kc;
    }
}

// ---------------------------------------------------------------------------
// DPP reduction helpers
// ---------------------------------------------------------------------------
__device__ __forceinline__ float dpp_xor1(float x) {
    return __int_as_float(__builtin_amdgcn_update_dpp(
        0, __float_as_int(x), 0xB1, 0xF, 0xF, false));
}
__device__ __forceinline__ float dpp_xor2(float x) {
    return __int_as_float(__builtin_amdgcn_update_dpp(
        0, __float_as_int(x), 0x4E, 0xF, 0xF, false));
}
__device__ __forceinline__ float dpp_hm(float x) {   // row_half_mirror
    return __int_as_float(__builtin_amdgcn_update_dpp(
        0, __float_as_int(x), 0x141, 0xF, 0xF, false));
}
__device__ __forceinline__ float red16(float x) {
    x += dpp_xor1(x);
    x += dpp_xor2(x);
    x += dpp_hm(x);
    x += __int_as_float(__builtin_amdgcn_update_dpp(0, __float_as_int(x), 0x140, 0xF, 0xF, false));
    return x;
}

// ---------------------------------------------------------------------------
// Phase A: per-(chunk,head) S-independent quantities (unchanged).
// ---------------------------------------------------------------------------
__global__ __launch_bounds__(256) void chunk_prep(
    const float* __restrict__ k_h, const float* __restrict__ la_h,
    const float* __restrict__ q_h, const float* __restrict__ kvb,
    const float* __restrict__ betab, float* __restrict__ pa)
{
    __shared__ float Ls[16][196];
    __shared__ float Ks[16][196];
    __shared__ float Qs[16][196];
    __shared__ float Ws[16][196];
    __shared__ float Xs[16][196];
    __shared__ float Ms[16][16];
    __shared__ float bs[16];

    const int tid = threadIdx.x;
    const int n = blockIdx.x >> 3, h = blockIdx.x & 7;
    const size_t g0 = ((size_t)h * TT + n * 16) * DK;
    float* blob = pa + (size_t)blockIdx.x * PABLK;

#pragma unroll
    for (int s = 0; s < 3; s++) {
        int off = (tid * 3 + s) * 4;
        int r = off / 192, c = off - r * 192;
        *(float4*)&Ks[r][c] = *(const float4*)(k_h + g0 + off);
        *(float4*)&Ls[r][c] = *(const float4*)(la_h + g0 + off);
        *(float4*)&Qs[r][c] = *(const float4*)(q_h + g0 + off);
    }
    if (tid < 16) bs[tid] = betab[(size_t)(n * 16 + tid) * HH + h];
    __syncthreads();

    if (tid < 192) {
        float g = 0.f;
#pragma unroll
        for (int i = 0; i < 16; i++) { g += Ls[i][tid]; Ls[i][tid] = g; }
    }
    __syncthreads();

#pragma unroll
    for (int s = 0; s < 12; s++) {
        int idx = s * 256 + tid;
        int i = idx / 192, d = idx - i * 192;
        float G = Ls[i][d];
        float eg = __expf(G), en = __expf(-G);
        float kk = Ks[i][d];
        Ws[i][d] = bs[i] * kk * eg;
        Qs[i][d] *= eg;
        Ks[i][d] = kk * en;
    }
    __syncthreads();

#pragma unroll
    for (int s = 0; s < 3; s++) {
        int off = (tid * 3 + s) * 4;
        int r = off / 192, c = off - r * 192;
        *(float4*)(blob + OQ + off) = *(const float4*)&Qs[r][c];
    }
    if (tid < 192) {
        float lam = __expf(Ls[15][tid]);
        blob[OLAM + tid] = lam;
#pragma unroll
        for (int j4 = 0; j4 < 4; j4++) {
            float4 v;
            v.x = Ks[j4 * 4 + 0][tid] * lam; v.y = Ks[j4 * 4 + 1][tid] * lam;
            v.z = Ks[j4 * 4 + 2][tid] * lam; v.w = Ks[j4 * 4 + 3][tid] * lam;
            *(float4*)(blob + OC + tid * 20 + j4 * 4) = v;
        }
        blob[OC + tid * 20 + 16] = lam;
        blob[OC + tid * 20 + 17] = 0.f;
        blob[OC + tid * 20 + 18] = 0.f; blob[OC + tid * 20 + 19] = 0.f;
    }
    {
        const int i = tid >> 4, j = tid & 15;
        float m = 0.f, p = 0.f;
#pragma unroll
        for (int d4 = 0; d4 < 48; d4++) {
            float4 w  = *(const float4*)&Ws[i][d4 * 4];
            float4 ka = *(const float4*)&Ks[j][d4 * 4];
            float4 qa = *(const float4*)&Qs[i][d4 * 4];
            m += w.x * ka.x + w.y * ka.y + w.z * ka.z + w.w * ka.w;
            p += qa.x * ka.x + qa.y * ka.y + qa.z * ka.z + qa.w * ka.w;
        }
        Ms[i][j] = (j < i) ? m : 0.f;
        blob[OPL + tid] = (j <= i) ? p : 0.f;
    }
    __syncthreads();

    float y[16], uu[16];
    const bool doY = (tid < 192);
    const bool doU = (tid >= 128);
    const int dcol = tid, ccol = tid - 128;
    if (doY) {
#pragma unroll
        for (int i = 0; i < 16; i++) y[i] = Ws[i][dcol];
#pragma unroll
        for (int i = 1; i < 16; i++)
#pragma unroll
            for (int j = 0; j < i; j++)
                y[i] = fmaf(-Ms[i][j], y[j], y[i]);
    }
    if (doU) {
#pragma unroll
        for (int i = 0; i < 16; i++)
            uu[i] = bs[i] * kvb[(size_t)(n * 16 + i) * HKV + h * (DNOPE + DV) + DNOPE + ccol];
#pragma unroll
        for (int i = 1; i < 16; i++)
#pragma unroll
            for (int j = 0; j < i; j++)
                uu[i] = fmaf(-Ms[i][j], uu[j], uu[i]);
    }
    if (doY) {
#pragma unroll
        for (int i = 0; i < 16; i++) Xs[i][dcol] = y[i];
    }
    __syncthreads();
#pragma unroll
    for (int s = 0; s < 3; s++) {
        int off = (tid * 3 + s) * 4;
        int r = off / 192, c = off - r * 192;
        *(float4*)(blob + OY + off) = *(const float4*)&Xs[r][c];
    }
    // u' written transposed, straight from registers: [128 cc][16 ti]
    if (doU) {
#pragma unroll
        for (int i4 = 0; i4 < 4; i4++) {
            float4 t;
            t.x = uu[i4 * 4 + 0]; t.y = uu[i4 * 4 + 1];
            t.z = uu[i4 * 4 + 2]; t.w = uu[i4 * 4 + 3];
            *(float4*)(blob + OU + (size_t)ccol * 16 + i4 * 4) = t;
        }
    }
}

// ---------------------------------------------------------------------------
// Phase A.5 (R19): lag-fold precompute. Gy_n = y_n.Kc_{n-1}, Gq_n = q~_n.Kc_{n-1};
// OY <- y_n*lam_{n-1}, OQ <- q~_n*lam_{n-1} in place.
// ---------------------------------------------------------------------------
__global__ __launch_bounds__(256) void chunk_prep2(float* __restrict__ pa)
{
    __shared__ float Kcs[16][204];   // [j][d] transposed Kc_{n-1}
    __shared__ float Ys[16][200];
    __shared__ float Qs[16][200];
    __shared__ float lamp[192];

    const int tid = threadIdx.x;
    const int n = blockIdx.x >> 3, h = blockIdx.x & 7;
    float* blob = pa + (size_t)blockIdx.x * PABLK;
    if (n == 0) {
        blob[OGY + tid] = 0.f;
        blob[OGQ + tid] = 0.f;
        return;
    }
    const float* pblob = pa + (size_t)((n - 1) * 8 + h) * PABLK;
    if (tid < 192) {
        lamp[tid] = pblob[OLAM + tid];
        float4 a  = *(const float4*)(pblob + OC + tid * 20);
        float4 b  = *(const float4*)(pblob + OC + tid * 20 + 4);
        float4 c  = *(const float4*)(pblob + OC + tid * 20 + 8);
        float4 d4 = *(const float4*)(pblob + OC + tid * 20 + 12);
        Kcs[0][tid]  = a.x;  Kcs[1][tid]  = a.y;  Kcs[2][tid]  = a.z;  Kcs[3][tid]  = a.w;
        Kcs[4][tid]  = b.x;  Kcs[5][tid]  = b.y;  Kcs[6][tid]  = b.z;  Kcs[7][tid]  = b.w;
        Kcs[8][tid]  = c.x;  Kcs[9][tid]  = c.y;  Kcs[10][tid] = c.z;  Kcs[11][tid] = c.w;
        Kcs[12][tid] = d4.x; Kcs[13][tid] = d4.y; Kcs[14][tid] = d4.z; Kcs[15][tid] = d4.w;
    }
#pragma unroll
    for (int s = 0; s < 3; s++) {
        int off = (tid * 3 + s) * 4;
        int r = off / 192, c2 = off - r * 192;
        *(float4*)&Ys[r][c2] = *(const float4*)(blob + OY + off);
        *(float4*)&Qs[r][c2] = *(const float4*)(blob + OQ + off);
    }
    __syncthreads();

    const int i = tid >> 4, j = tid & 15;
    float gy0 = 0.f, gy1 = 0.f, gq0 = 0.f, gq1 = 0.f;
#pragma unroll
    for (int d4 = 0; d4 < 48; d4++) {
        float4 kv = *(const float4*)&Kcs[j][d4 * 4];
        float4 yv = *(const float4*)&Ys[i][d4 * 4];
        float4 qv = *(const float4*)&Qs[i][d4 * 4];
        gy0 = fmaf(yv.x, kv.x, gy0); gy1 = fmaf(yv.y, kv.y, gy1);
        gy0 = fmaf(yv.z, kv.z, gy0); gy1 = fmaf(yv.w, kv.w, gy1);
        gq0 = fmaf(qv.x, kv.x, gq0); gq1 = fmaf(qv.y, kv.y, gq1);
        gq0 = fmaf(qv.z, kv.z, gq0); gq1 = fmaf(qv.w, kv.w, gq1);
    }
    blob[OGY + tid] = gy0 + gy1;
    blob[OGQ + tid] = gq0 + gq1;

#pragma unroll
    for (int s = 0; s < 3; s++) {
        int off = (tid * 3 + s) * 4;
        int r = off / 192, c2 = off - r * 192;
        float4 yv = *(const float4*)&Ys[r][c2];
        float4 qv = *(const float4*)&Qs[r][c2];
        float4 lv = *(const float4*)&lamp[c2];
        yv.x *= lv.x; yv.y *= lv.y; yv.z *= lv.z; yv.w *= lv.w;
        qv.x *= lv.x; qv.y *= lv.y; qv.z *= lv.z; qv.w *= lv.w;
        *(float4*)(blob + OY + off) = yv;
        *(float4*)(blob + OQ + off) = qv;
    }
}

// ---------------------------------------------------------------------------
// Phase B — R19/R6 version verbatim (best measured: 99.0 µs). Lag-folded
// single-barrier segments, 256 blocks x 1024 threads, 4-buffer distance-2
// staging, S/us double-buffered.
// ---------------------------------------------------------------------------
__global__ __launch_bounds__(1024) void kda_chunk(
    const float* __restrict__ pa, unsigned short* __restrict__ obh,
    unsigned short* __restrict__ obl)
{
    __shared__ float Cb[4][3840];
    __shared__ float Pb[4][256];
    __shared__ float Gyb[4][256];
    __shared__ float Gqb[4][256];
    __shared__ float ubs[4][64];    // u' slice [4 cc][16 ti]
    __shared__ float lbs[4][192];
    __shared__ float Ss[2][4][200]; // state double buffer [cc][d]
    __shared__ float us[2][64];     // u double buffer [cc*16+ti]

    const int tid = threadIdx.x;
    const int w = tid >> 6, lane = tid & 63;
    const int h = blockIdx.x & 7, cg = blockIdx.x >> 3;   // XCD swizzle
    const int c0 = cg * 4;

    const int ti = w;               // wave = time row (16 waves)
    const int cc = lane >> 4;       // 4 channels
    const int dg = lane & 15;       // 16 d-groups of 12
    const int dbase = dg * 12;

    auto stage = [&](int buf, int n) {
        const float* blob = pa + (size_t)(n * 8 + h) * PABLK;
        if (w < 15) {
            gl_lds16(blob + OC + w * 256 + lane * 4, &Cb[buf][w * 256]);
            if (w == 0) {
                gl_lds16(blob + OGY + lane * 4, &Gyb[buf][0]);
            } else if (w == 1) {
                gl_lds16(blob + OGQ + lane * 4, &Gqb[buf][0]);
            } else if (w == 2) {
                if (lane < 16)
                    gl_lds16(blob + OU + c0 * 16 + lane * 4, &ubs[buf][0]);
            } else if (w == 3) {
                if (lane < 48)
                    gl_lds16(blob + OLAM + lane * 4, &lbs[buf][0]);
            }
        } else {
            gl_lds16(blob + OPL + lane * 4, &Pb[buf][0]);
        }
    };

    auto ldYQ = [&](int n, float4 (&Y)[3], float4 (&Q)[3]) {
        const float* blob = pa + (size_t)(n * 8 + h) * PABLK;
        const float* py_ = blob + OY + ti * 192 + dbase;
        const float* pq_ = blob + OQ + ti * 192 + dbase;
#pragma unroll
        for (int s = 0; s < 3; s++) {
            Y[s] = *(const float4*)(py_ + s * 4);
            Q[s] = *(const float4*)(pq_ + s * 4);
        }
    };

    auto body = [&](int n, float4 (&Yc)[3], float4 (&Qc)[3], float& zqc) {
        const int p = n & 1, q = p ^ 1;
        const int bn = n & 3, bp = (n - 1) & 3;

        const float* Sp = &Ss[q][cc][dbase];
        float4 sv0 = *(const float4*)Sp;
        float4 sv1 = *(const float4*)(Sp + 4);
        float4 sv2 = *(const float4*)(Sp + 8);
        float upv = us[q][cc * 16 + dg];
        float gyv = Gyb[bn][ti * 16 + dg];
        float gqv = Gqb[bn][ti * 16 + dg];
        float ubv = ubs[bn][cc * 16 + ti];

        float py0 = gyv * upv, py1 = 0.f;
        float pq0 = gqv * upv, pq1 = 0.f;
        py0 = fmaf(Yc[0].x, sv0.x, py0); py1 = fmaf(Yc[0].y, sv0.y, py1);
        py0 = fmaf(Yc[0].z, sv0.z, py0); py1 = fmaf(Yc[0].w, sv0.w, py1);
        pq0 = fmaf(Qc[0].x, sv0.x, pq0); pq1 = fmaf(Qc[0].y, sv0.y, pq1);
        pq0 = fmaf(Qc[0].z, sv0.z, pq0); pq1 = fmaf(Qc[0].w, sv0.w, pq1);
        py0 = fmaf(Yc[1].x, sv1.x, py0); py1 = fmaf(Yc[1].y, sv1.y, py1);
        py0 = fmaf(Yc[1].z, sv1.z, py0); py1 = fmaf(Yc[1].w, sv1.w, py1);
        pq0 = fmaf(Qc[1].x, sv1.x, pq0); pq1 = fmaf(Qc[1].y, sv1.y, pq1);
        pq0 = fmaf(Qc[1].z, sv1.z, pq0); pq1 = fmaf(Qc[1].w, sv1.w, pq1);
        py0 = fmaf(Yc[2].x, sv2.x, py0); py1 = fmaf(Yc[2].y, sv2.y, py1);
        py0 = fmaf(Yc[2].z, sv2.z, py0); py1 = fmaf(Yc[2].w, sv2.w, py1);
        pq0 = fmaf(Qc[2].x, sv2.x, pq0); pq1 = fmaf(Qc[2].y, sv2.y, pq1);
        pq0 = fmaf(Qc[2].z, sv2.z, pq0); pq1 = fmaf(Qc[2].w, sv2.w, pq1);

        float zy = red16(py0 + py1);
        float zq = red16(pq0 + pq1);
        if (dg == 0) us[p][cc * 16 + ti] = ubv - zy;

        if (n > 0) {
            // o_{n-1} = zq_{n-1} + P_{n-1}.u_{n-1}
            float oa = red16((dg <= ti) ? Pb[bp][ti * 16 + dg] * upv : 0.f);
            if (dg == 0) {
                float ov = zqc + oa;
                if (isnan(ov)) ov = 0.f;
                else if (isinf(ov)) ov = ov > 0.f ? 1e4f : -1e4f;
                size_t oi = (size_t)((n - 1) * 16 + ti) * (HH * DV) + h * DV + c0 + cc;
                unsigned short hb = f2bf_rn(ov);
                obh[oi] = hb;
                obl[oi] = f2bf_rn(ov - bf2f(hb));
            }
            // S_n = lam_{n-1} o S_{n-1} + Kc_{n-1}.u_{n-1}
            if (tid < 768) {
                const int d = tid >> 2, c = tid & 3;
                float sprev = Ss[q][c][d];
                const float4* U4 = (const float4*)&us[q][c * 16];
                float4 u0 = U4[0], u1 = U4[1], u2v = U4[2], u3 = U4[3];
                const float4* C4 = (const float4*)&Cb[bp][d * 20];
                float4 k0 = C4[0], k1 = C4[1], k2 = C4[2], k3 = C4[3];
                float a0 = lbs[bp][d] * sprev, a1 = 0.f;
                a0 = fmaf(k0.x, u0.x,  a0); a1 = fmaf(k0.y, u0.y,  a1);
                a0 = fmaf(k0.z, u0.z,  a0); a1 = fmaf(k0.w, u0.w,  a1);
                a0 = fmaf(k1.x, u1.x,  a0); a1 = fmaf(k1.y, u1.y,  a1);
                a0 = fmaf(k1.z, u1.z,  a0); a1 = fmaf(k1.w, u1.w,  a1);
                a0 = fmaf(k2.x, u2v.x, a0); a1 = fmaf(k2.y, u2v.y, a1);
                a0 = fmaf(k2.z, u2v.z, a0); a1 = fmaf(k2.w, u2v.w, a1);
                a0 = fmaf(k3.x, u3.x,  a0); a1 = fmaf(k3.y, u3.y,  a1);
                a0 = fmaf(k3.z, u3.z,  a0); a1 = fmaf(k3.w, u3.w,  a1);
                Ss[p][c][d] = a0 + a1;
            }
        }
        zqc = zq;
    };

#define SEG_BAR asm volatile("s_waitcnt lgkmcnt(0)\n\ts_barrier" ::: "memory")

    // init
    for (int i = tid; i < 1600; i += 1024) ((float*)Ss)[i] = 0.f;
    if (tid < 128) ((float*)us)[tid] = 0.f;
    stage(0, 0);
    stage(1, 1);
    asm volatile("" ::: "memory");
    float4 Ya[3], Qa[3], Yb[3], Qb[3];
    ldYQ(0, Ya, Qa);
    float zqc = 0.f;
    asm volatile("s_waitcnt vmcnt(0) lgkmcnt(0)\n\ts_barrier" ::: "memory");

    for (int n = 0; n < NBODY; n += 2) {
        if (n + 2 < NBODY) stage((n + 2) & 3, n + 2);
        asm volatile("" ::: "memory");
        ldYQ(n + 1, Yb, Qb);
        body(n, Ya, Qa, zqc);
        SEG_BAR;
        if (n + 3 < NBODY) stage((n + 3) & 3, n + 3);
        asm volatile("" ::: "memory");
        if (n + 2 < NBODY) ldYQ(n + 2, Ya, Qa);
        body(n + 1, Yb, Qb, zqc);
        SEG_BAR;
    }
    // epilogue: o_63 = zq_63 + P_63 . u_63
    {
        float upv = us[1][cc * 16 + dg];                 // u_63 (63&1 == 1)
        float oa = red16((dg <= ti) ? Pb[(NBODY - 1) & 3][ti * 16 + dg] * upv : 0.f);
        if (dg == 0) {
            float ov = zqc + oa;
            if (isnan(ov)) ov = 0.f;
            else if (isinf(ov)) ov = ov > 0.f ? 1e4f : -1e4f;
            size_t oi = (size_t)((NBODY - 1) * 16 + ti) * (HH * DV) + h * DV + c0 + cc;
            unsigned short hb = f2bf_rn(ov);
            obh[oi] = hb;
            obl[oi] = f2bf_rn(ov - bf2f(hb));
        }
    }
#undef SEG_BAR
}

// ---------------------------------------------------------------------------
extern "C" void kernel_launch(void* const* d_in, const int* in_sizes, int n_in,
                              void* d_out, int out_size, void* d_ws, size_t ws_size,
                              hipStream_t stream)
{
    const float* x         = (const float*)d_in[0];
    // d_in[1] = cos, d_in[2] = sin : unused by the reference
    const float* wq_a      = (const float*)d_in[3];
    const float* q_norm_w  = (const float*)d_in[4];
    const float* wq_b      = (const float*)d_in[5];
    const float* wkv_a     = (const float*)d_in[6];
    const float* kv_norm_w = (const float*)d_in[7];
    const float* wkv_b     = (const float*)d_in[8];
    const float* wg_w      = (const float*)d_in[9];
    const float* wg_b      = (const float*)d_in[10];
    const float* wb        = (const float*)d_in[11];
    const float* wo        = (const float*)d_in[12];
    float* out = (float*)d_out;

    float* ws = (float*)d_ws;
    float* xq     = ws;                        // T x 768 (f32, gemm1 out)
    float* kv_all = xq     + TT * QLR;         // T x 576
    float* agraw  = kv_all + TT * (KVLR + DROPE); // T x 1536 (dead after logsig)
    float* qnraw  = agraw  + TT * HDK;         // T x 1536
    float* kvb    = qnraw  + TT * HDK;         // T x 2048
    float* la_h   = kvb    + TT * HKV;         // 8 x 1024 x 192
    float* q_h    = la_h   + TT * HDK;
    float* k_h    = q_h    + TT * HDK;
    float* betab  = k_h    + TT * HDK;         // T x 8
    float* pa     = betab  + TT * HH;          // 512 x PABLK (26.6 MB)
    float* tail   = pa     + 512 * PABLK;

    unsigned short* wo_h  = (unsigned short*)tail;          // 1024*1024
    unsigned short* wo_l  = wo_h  + 1048576;
    unsigned short* xh    = wo_l  + 1048576;                // 1024*1024
    unsigned short* xl    = xh    + 1048576;
    unsigned short* xqh   = xl    + 1048576;                // 1024*768
    unsigned short* xql   = xqh   + 786432;
    unsigned short* kvnh  = xql   + 786432;                 // 1024*512
    unsigned short* kvnl  = kvnh  + 524288;

    unsigned short* wqa_h  = (unsigned short*)pa;           // 768n x 1024k
    unsigned short* wqa_l  = wqa_h  + 786432;
    unsigned short* wkva_h = wqa_l  + 786432;               // 576n x 1024k
    unsigned short* wkva_l = wkva_h + 589824;
    unsigned short* wgw_h  = wkva_l + 589824;               // 1536n x 1024k
    unsigned short* wgw_l  = wgw_h  + 1572864;
    unsigned short* wqb_h  = wgw_l  + 1572864;              // 1536n x 768k
    unsigned short* wqb_l  = wqb_h  + 1179648;
    unsigned short* wkvb_h = wqb_l  + 1179648;              // 2048n x 512k
    unsigned short* wkvb_l = wkvb_h + 1048576;

    unsigned short* obh = (unsigned short*)agraw;           // 1024*1024
    unsigned short* obl = obh + 1048576;

    dim3 blk(256);

    wconv<<<dim3(192 + 144 + 384), blk, 0, stream>>>(
        wq_a, wqa_h, wqa_l, DIM, QLR, 192,
        wkv_a, wkva_h, wkva_l, DIM, KVLR + DROPE, 144,
        wg_w, wgw_h, wgw_l, DIM, HDK, 384);
    wconv<<<dim3(288 + 256 + 256), blk, 0, stream>>>(
        wq_b, wqb_h, wqb_l, QLR, HDK, 288,
        wkv_b, wkvb_h, wkvb_l, KVLR, HKV, 256,
        wo, wo_h, wo_l, DIM, DIM, 256);

    aconv<<<dim3(TT * DIM / (256 * 8)), blk, 0, stream>>>(x, xh, xl);

    // 128x64 tiles -> grid (sum NT, M/128), 256 threads
    gemm_bt<<<dim3(12 + 9 + 24, 8), dim3(256), 0, stream>>>(
        xh, xl, wqa_h, wqa_l, xq, DIM, QLR, 12,
        xh, xl, wkva_h, wkva_l, kv_all, DIM, KVLR + DROPE, 9,
        xh, xl, wgw_h, wgw_l, agraw, DIM, HDK, 24);

    rmsnorm_bf2<<<dim3(2 * TT), blk, 0, stream>>>(
        xq, q_norm_w, xqh, xql,
        kv_all, kv_norm_w, kvnh, kvnl);

    gemm_bt<<<dim3(24 + 32, 8), dim3(256), 0, stream>>>(
        xqh, xql, wqb_h, wqb_l, qnraw, QLR, HDK, 24,
        kvnh, kvnl, wkvb_h, wkvb_l, kvb, KVLR, HKV, 32,
        xh, xl, wqa_h, wqa_l, xq, DIM, QLR, 0);

    small_fused<<<dim3(6144 + 2048 + 2048), blk, 0, stream>>>(
        agraw, wg_b, la_h,
        x, wb, betab,
        qnraw, kvb, kv_all, q_h, k_h);

    chunk_prep<<<512, blk, 0, stream>>>(k_h, la_h, q_h, kvb, betab, pa);
    chunk_prep2<<<512, blk, 0, stream>>>(pa);
    kda_chunk<<<256, dim3(1024), 0, stream>>>(pa, obh, obl);

    gemm_bt<<<dim3(16, 8), dim3(256), 0, stream>>>(
        obh, obl, wo_h, wo_l, out, DIM, DIM, 16,
        xh, xl, wqa_h, wqa_l, xq, DIM, QLR, 0,
        xh, xl, wqa_h, wqa_l, xq, DIM, QLR, 0);
}

// Round 8
// 312.979 us; speedup vs baseline: 1.0641x; 1.0641x over previous
//
#include <hip/hip_runtime.h>
#include <hip/hip_bf16.h>
#include <math.h>

// Problem constants
#define TT 1024
#define DIM 1024
#define HH 8
#define QLR 768
#define KVLR 512
#define DNOPE 128
#define DROPE 64
#define DV 128
#define DK 192            // DNOPE + DROPE
#define HDK (HH*DK)       // 1536
#define HKV (HH*(DNOPE+DV)) // 2048

// Phase-A blob layout (floats) per (chunk n, head h):
#define OY   0
#define OQ   3072
#define OC   6144         // KcT [192][20] padded; slot 16 of each row = lam[d]
#define OPL  9984
#define OU   10240        // u' transposed: [128 cc][16 ti]
#define OLAM 12288
#define PABLK 12480

typedef __attribute__((ext_vector_type(8))) short short8;
typedef __attribute__((ext_vector_type(4))) float f32x4;

// ---------------------------------------------------------------------------
// bf16 split helpers
// ---------------------------------------------------------------------------
__device__ __forceinline__ unsigned short f2bf_rn(float f) {
    unsigned u = __float_as_uint(f);
    unsigned lsb = (u >> 16) & 1u;
    u += 0x7fffu + lsb;
    return (unsigned short)(u >> 16);
}
__device__ __forceinline__ float bf2f(unsigned short h) {
    return __uint_as_float(((unsigned)h) << 16);
}

// ---------------------------------------------------------------------------
// Weight transpose+split: W[K][N] f32 -> Wt_h[N][K], Wt_l[N][K] bf16.
// ---------------------------------------------------------------------------
__global__ __launch_bounds__(256) void wconv(
    const float* __restrict__ W0, unsigned short* __restrict__ H0,
    unsigned short* __restrict__ L0, int K0, int N0, int T0,
    const float* __restrict__ W1, unsigned short* __restrict__ H1,
    unsigned short* __restrict__ L1, int K1, int N1, int T1,
    const float* __restrict__ W2, unsigned short* __restrict__ H2,
    unsigned short* __restrict__ L2, int K2, int N2, int T2)
{
    __shared__ float Ls[64][65];
    int bx = blockIdx.x;
    const float* W; unsigned short* H; unsigned short* L; int K, N;
    if (bx < T0)           { W = W0; H = H0; L = L0; K = K0; N = N0; }
    else if (bx < T0 + T1) { bx -= T0; W = W1; H = H1; L = L1; K = K1; N = N1; }
    else                   { bx -= T0 + T1; W = W2; H = H2; L = L2; K = K2; N = N2; }

    const int NT = N >> 6;
    const int kt = bx / NT, nt = bx - kt * NT;
    const int k0 = kt * 64, n0 = nt * 64;
    const int tid = threadIdx.x;
    const int r = tid >> 2, c = (tid & 3) * 16;

#pragma unroll
    for (int i = 0; i < 4; i++)
        *(float4*)&Ls[r][c + i * 4] =
            *(const float4*)&W[(size_t)(k0 + r) * N + n0 + c + i * 4];
    __syncthreads();

    const int nr = tid >> 2, kc = (tid & 3) * 16;
    unsigned short hb[16], lb[16];
#pragma unroll
    for (int j = 0; j < 16; j++) {
        float v = Ls[kc + j][nr];
        unsigned short h = f2bf_rn(v);
        hb[j] = h;
        lb[j] = f2bf_rn(v - bf2f(h));
    }
    size_t ob = (size_t)(n0 + nr) * K + k0 + kc;
    *(float4*)&H[ob]     = ((float4*)hb)[0];
    *(float4*)&H[ob + 8] = ((float4*)hb)[1];
    *(float4*)&L[ob]     = ((float4*)lb)[0];
    *(float4*)&L[ob + 8] = ((float4*)lb)[1];
}

// ---------------------------------------------------------------------------
// Activation split: A f32 -> H, L bf16.
// ---------------------------------------------------------------------------
__global__ __launch_bounds__(256) void aconv(
    const float* __restrict__ A, unsigned short* __restrict__ H,
    unsigned short* __restrict__ L)
{
    int i = (blockIdx.x * 256 + threadIdx.x) * 8;
    float4 v0 = *(const float4*)&A[i];
    float4 v1 = *(const float4*)&A[i + 4];
    float vv[8] = {v0.x, v0.y, v0.z, v0.w, v1.x, v1.y, v1.z, v1.w};
    unsigned short hb[8], lb[8];
#pragma unroll
    for (int j = 0; j < 8; j++) {
        unsigned short h = f2bf_rn(vv[j]);
        hb[j] = h;
        lb[j] = f2bf_rn(vv[j] - bf2f(h));
    }
    *(float4*)&H[i] = *(float4*)hb;
    *(float4*)&L[i] = *(float4*)lb;
}

// ---------------------------------------------------------------------------
// bf16x3 MFMA GEMM (R10 version — best measured config; R21/R22 128x64
// gl_lds variants measured +12us total and are abandoned).
// ---------------------------------------------------------------------------
__global__ __launch_bounds__(128) void gemm_bt(
    const unsigned short* __restrict__ Ah0, const unsigned short* __restrict__ Al0,
    const unsigned short* __restrict__ Bh0, const unsigned short* __restrict__ Bl0,
    float* __restrict__ C0, int K0, int N0, int T0,
    const unsigned short* __restrict__ Ah1, const unsigned short* __restrict__ Al1,
    const unsigned short* __restrict__ Bh1, const unsigned short* __restrict__ Bl1,
    float* __restrict__ C1, int K1, int N1, int T1,
    const unsigned short* __restrict__ Ah2, const unsigned short* __restrict__ Al2,
    const unsigned short* __restrict__ Bh2, const unsigned short* __restrict__ Bl2,
    float* __restrict__ C2, int K2, int N2, int T2)
{
    __shared__ unsigned short Ahs[64 * 40], Als[64 * 40];
    __shared__ unsigned short Bhs[64 * 40], Bls[64 * 40];

    int bx = blockIdx.x;
    const unsigned short *Ah, *Al, *Bh, *Bl; float* C; int K, N;
    if (bx < T0) {
        Ah = Ah0; Al = Al0; Bh = Bh0; Bl = Bl0; C = C0; K = K0; N = N0;
    } else if (bx < T0 + T1) {
        bx -= T0; Ah = Ah1; Al = Al1; Bh = Bh1; Bl = Bl1; C = C1; K = K1; N = N1;
    } else {
        bx -= T0 + T1; Ah = Ah2; Al = Al2; Bh = Bh2; Bl = Bl2; C = C2; K = K2; N = N2;
    }

    const int tid = threadIdx.x;
    const int w = tid >> 6, l = tid & 63;
    const int q = l >> 4, m16 = l & 15;
    const int bm = blockIdx.y * 64, bn = bx * 64;

    const int c0i = tid * 2, c1i = tid * 2 + 1;
    const int r0 = c0i >> 2, o0 = (c0i & 3) * 8;
    const int r1 = c1i >> 2, o1 = (c1i & 3) * 8;
    const unsigned short* pAh0 = Ah + (size_t)(bm + r0) * K + o0;
    const unsigned short* pAh1 = Ah + (size_t)(bm + r1) * K + o1;
    const unsigned short* pAl0 = Al + (size_t)(bm + r0) * K + o0;
    const unsigned short* pAl1 = Al + (size_t)(bm + r1) * K + o1;
    const unsigned short* pBh0 = Bh + (size_t)(bn + r0) * K + o0;
    const unsigned short* pBh1 = Bh + (size_t)(bn + r1) * K + o1;
    const unsigned short* pBl0 = Bl + (size_t)(bn + r0) * K + o0;
    const unsigned short* pBl1 = Bl + (size_t)(bn + r1) * K + o1;

    f32x4 acc[2][4];
#pragma unroll
    for (int i = 0; i < 2; i++)
#pragma unroll
        for (int j = 0; j < 4; j++)
            acc[i][j] = (f32x4){0.f, 0.f, 0.f, 0.f};

    float4 vAh0 = *(const float4*)pAh0, vAh1 = *(const float4*)pAh1;
    float4 vAl0 = *(const float4*)pAl0, vAl1 = *(const float4*)pAl1;
    float4 vBh0 = *(const float4*)pBh0, vBh1 = *(const float4*)pBh1;
    float4 vBl0 = *(const float4*)pBl0, vBl1 = *(const float4*)pBl1;

    for (int k0 = 0;; k0 += 32) {
        __syncthreads();
        *(float4*)&Ahs[r0 * 40 + o0] = vAh0; *(float4*)&Ahs[r1 * 40 + o1] = vAh1;
        *(float4*)&Als[r0 * 40 + o0] = vAl0; *(float4*)&Als[r1 * 40 + o1] = vAl1;
        *(float4*)&Bhs[r0 * 40 + o0] = vBh0; *(float4*)&Bhs[r1 * 40 + o1] = vBh1;
        *(float4*)&Bls[r0 * 40 + o0] = vBl0; *(float4*)&Bls[r1 * 40 + o1] = vBl1;
        __syncthreads();

        const bool more = (k0 + 32) < K;
        if (more) {
            const int kn = k0 + 32;
            vAh0 = *(const float4*)(pAh0 + kn); vAh1 = *(const float4*)(pAh1 + kn);
            vAl0 = *(const float4*)(pAl0 + kn); vAl1 = *(const float4*)(pAl1 + kn);
            vBh0 = *(const float4*)(pBh0 + kn); vBh1 = *(const float4*)(pBh1 + kn);
            vBl0 = *(const float4*)(pBl0 + kn); vBl1 = *(const float4*)(pBl1 + kn);
        }

        short8 fah[2], fal[2], fbh[4], fbl[4];
#pragma unroll
        for (int mt = 0; mt < 2; mt++) {
            const int row = w * 32 + mt * 16 + m16;
            fah[mt] = *(const short8*)&Ahs[row * 40 + q * 8];
            fal[mt] = *(const short8*)&Als[row * 40 + q * 8];
        }
#pragma unroll
        for (int nt = 0; nt < 4; nt++) {
            const int row = nt * 16 + m16;
            fbh[nt] = *(const short8*)&Bhs[row * 40 + q * 8];
            fbl[nt] = *(const short8*)&Bls[row * 40 + q * 8];
        }
#pragma unroll
        for (int mt = 0; mt < 2; mt++)
#pragma unroll
            for (int nt = 0; nt < 4; nt++) {
                acc[mt][nt] = __builtin_amdgcn_mfma_f32_16x16x32_bf16(
                    fah[mt], fbh[nt], acc[mt][nt], 0, 0, 0);
                acc[mt][nt] = __builtin_amdgcn_mfma_f32_16x16x32_bf16(
                    fah[mt], fbl[nt], acc[mt][nt], 0, 0, 0);
                acc[mt][nt] = __builtin_amdgcn_mfma_f32_16x16x32_bf16(
                    fal[mt], fbh[nt], acc[mt][nt], 0, 0, 0);
            }
        if (!more) break;
    }

#pragma unroll
    for (int mt = 0; mt < 2; mt++)
#pragma unroll
        for (int nt = 0; nt < 4; nt++) {
            const int mrow = bm + w * 32 + mt * 16 + q * 4;
            const int ncol = bn + nt * 16 + m16;
#pragma unroll
            for (int r = 0; r < 4; r++)
                C[(size_t)(mrow + r) * N + ncol] = acc[mt][nt][r];
        }
}

// ---------------------------------------------------------------------------
// Fused RMSNorm (both norms in one launch; region-routed) -> bf16 hi/lo
// ---------------------------------------------------------------------------
__global__ __launch_bounds__(256) void rmsnorm_bf2(
    const float* __restrict__ in0, const float* __restrict__ w0,
    unsigned short* __restrict__ oh0, unsigned short* __restrict__ ol0,
    const float* __restrict__ in1, const float* __restrict__ w1,
    unsigned short* __restrict__ oh1, unsigned short* __restrict__ ol1)
{
    int bx = blockIdx.x;
    const float* in; const float* w; unsigned short *oh, *ol;
    int t, stride, ncols; float inv_n;
    if (bx < TT) {
        t = bx; in = in0; w = w0; oh = oh0; ol = ol0;
        stride = QLR; ncols = QLR; inv_n = 1.f / QLR;
    } else {
        t = bx - TT; in = in1; w = w1; oh = oh1; ol = ol1;
        stride = KVLR + DROPE; ncols = KVLR; inv_n = 1.f / KVLR;
    }
    const int tid = threadIdx.x;
    const float* row = in + (size_t)t * stride;
    float ss = 0.f;
    for (int c = tid; c < ncols; c += 256) { float v = row[c]; ss += v * v; }
#pragma unroll
    for (int m = 1; m < 64; m <<= 1) ss += __shfl_xor(ss, m);
    __shared__ float red[4];
    if ((tid & 63) == 0) red[tid >> 6] = ss;
    __syncthreads();
    float tot = red[0] + red[1] + red[2] + red[3];
    float scale = rsqrtf(tot * inv_n + 1e-5f);
    for (int c = tid; c < ncols; c += 256) {
        float v = row[c] * scale * w[c];
        unsigned short h = f2bf_rn(v);
        oh[(size_t)t * ncols + c] = h;
        ol[(size_t)t * ncols + c] = f2bf_rn(v - bf2f(h));
    }
}

// ---------------------------------------------------------------------------
// DPP reduction helpers
// ---------------------------------------------------------------------------
__device__ __forceinline__ float dpp_xor1(float x) {
    return __int_as_float(__builtin_amdgcn_update_dpp(
        0, __float_as_int(x), 0xB1, 0xF, 0xF, false));
}
__device__ __forceinline__ float dpp_xor2(float x) {
    return __int_as_float(__builtin_amdgcn_update_dpp(
        0, __float_as_int(x), 0x4E, 0xF, 0xF, false));
}
__device__ __forceinline__ float dpp_hm(float x) {   // row_half_mirror
    return __int_as_float(__builtin_amdgcn_update_dpp(
        0, __float_as_int(x), 0x141, 0xF, 0xF, false));
}
__device__ __forceinline__ float dpp_rm(float x) {   // row_mirror
    return __int_as_float(__builtin_amdgcn_update_dpp(
        0, __float_as_int(x), 0x140, 0xF, 0xF, false));
}
__device__ __forceinline__ float dpp_b15(float x) {  // row_bcast15
    return __int_as_float(__builtin_amdgcn_update_dpp(
        0, __float_as_int(x), 0x142, 0xF, 0xF, false));
}
__device__ __forceinline__ float red16(float x) {
    x += dpp_xor1(x);
    x += dpp_xor2(x);
    x += dpp_hm(x);
    x += dpp_rm(x);
    return x;
}
// 32-lane sum; result valid at lanes with (lane&31) in [16,32)
__device__ __forceinline__ float red32v(float x) {
    x += dpp_xor1(x);
    x += dpp_xor2(x);
    x += dpp_hm(x);
    x += dpp_rm(x);     // full 16-row sums in all lanes
    x += dpp_b15(x);    // rows 1,3 receive row 0,2 sums
    return x;
}

__device__ __forceinline__ void gl_lds16(const float* g, float* l) {
    __builtin_amdgcn_global_load_lds(
        (const __attribute__((address_space(1))) void*)g,
        (__attribute__((address_space(3))) void*)l, 16, 0, 0);
}

// ---------------------------------------------------------------------------
// Phase A — R23: small_fused FUSED IN. Per (chunk n, head h) block this now
// computes from RAW gemm outputs: logsig(agraw+bias) -> Ls; l2norm scales
// for q (qnraw) and k (kvb nope + kv_all pe); beta = sigmoid(x.wb).
// Removes the 10240-block small_fused launch and the 36MB la_h/q_h/k_h
// intermediate round-trip (scattered writes). Downstream math unchanged.
// OU stored transposed [128 cc][16 ti].
// ---------------------------------------------------------------------------
__global__ __launch_bounds__(256) void chunk_prep(
    const float* __restrict__ qnraw, const float* __restrict__ agraw,
    const float* __restrict__ wg_b, const float* __restrict__ kvb,
    const float* __restrict__ kv_all, const float* __restrict__ x,
    const float* __restrict__ wb, float* __restrict__ pa)
{
    __shared__ float Ls[16][196];
    __shared__ float Ks[16][196];
    __shared__ float Qs[16][196];
    __shared__ float Ws[16][196];
    __shared__ float Xs[16][196];
    __shared__ float Ms[16][16];
    __shared__ float bs[16];
    __shared__ float kn[16], qn[16];

    const int tid = threadIdx.x;
    const int n = blockIdx.x >> 3, h = blockIdx.x & 7;
    const int t0 = n * 16;
    float* blob = pa + (size_t)blockIdx.x * PABLK;

    // ---- load raw Q / gate(->logsig) / K --------------------------------
#pragma unroll
    for (int s = 0; s < 3; s++) {
        int off = (tid * 3 + s) * 4;
        int r = off / 192, c = off - r * 192;
        *(float4*)&Qs[r][c] =
            *(const float4*)(qnraw + (size_t)(t0 + r) * HDK + h * DK + c);
        float4 g4 = *(const float4*)(agraw + (size_t)(t0 + r) * HDK + h * DK + c);
        float4 b4 = *(const float4*)(wg_b + h * DK + c);
        float4 la;
        {
            float z;
            z = g4.x + b4.x; la.x = fminf(z, 0.f) - log1pf(__expf(-fabsf(z)));
            z = g4.y + b4.y; la.y = fminf(z, 0.f) - log1pf(__expf(-fabsf(z)));
            z = g4.z + b4.z; la.z = fminf(z, 0.f) - log1pf(__expf(-fabsf(z)));
            z = g4.w + b4.w; la.w = fminf(z, 0.f) - log1pf(__expf(-fabsf(z)));
        }
        *(float4*)&Ls[r][c] = la;
        float4 kv;
        if (c < DNOPE)
            kv = *(const float4*)(kvb + (size_t)(t0 + r) * HKV + h * (DNOPE + DV) + c);
        else
            kv = *(const float4*)(kv_all + (size_t)(t0 + r) * (KVLR + DROPE) + KVLR + (c - DNOPE));
        *(float4*)&Ks[r][c] = kv;
    }
    // ---- beta: wave wv handles rows wv*4..wv*4+3 ------------------------
    {
        const int lane = tid & 63, wv = tid >> 6;
#pragma unroll
        for (int rr = 0; rr < 4; rr++) {
            const int r = wv * 4 + rr;
            const float* xr = x + (size_t)(t0 + r) * DIM;
            float ssum = 0.f;
            for (int e = lane; e < DIM; e += 64) ssum += xr[e] * wb[e * HH + h];
#pragma unroll
            for (int m = 1; m < 64; m <<= 1) ssum += __shfl_xor(ssum, m);
            if (lane == 0) bs[r] = 1.f / (1.f + expf(-ssum));
        }
    }
    __syncthreads();

    // ---- l2norm scales (16 threads per row, red16 within 16-lane group) -
    {
        const int i = tid >> 4, j = tid & 15;
        float sq = 0.f, sk = 0.f;
#pragma unroll
        for (int c4 = 0; c4 < 3; c4++) {
            float4 q4 = *(const float4*)&Qs[i][j * 12 + c4 * 4];
            float4 k4 = *(const float4*)&Ks[i][j * 12 + c4 * 4];
            sq += q4.x * q4.x + q4.y * q4.y + q4.z * q4.z + q4.w * q4.w;
            sk += k4.x * k4.x + k4.y * k4.y + k4.z * k4.z + k4.w * k4.w;
        }
        sq = red16(sq);
        sk = red16(sk);
        if (j == 0) {
            qn[i] = rsqrtf(sq + 1e-6f) * 0.07216878364870323f;  // * DK^-0.5
            kn[i] = rsqrtf(sk + 1e-6f);
        }
    }
    // ---- cumulative gate sums -------------------------------------------
    if (tid < 192) {
        float g = 0.f;
#pragma unroll
        for (int i = 0; i < 16; i++) { g += Ls[i][tid]; Ls[i][tid] = g; }
    }
    __syncthreads();

    // ---- scale by exp(G) and norms --------------------------------------
#pragma unroll
    for (int s = 0; s < 12; s++) {
        int idx = s * 256 + tid;
        int i = idx / 192, d = idx - i * 192;
        float G = Ls[i][d];
        float eg = __expf(G), en = __expf(-G);
        float kk = Ks[i][d] * kn[i];
        Ws[i][d] = bs[i] * kk * eg;
        Qs[i][d] = Qs[i][d] * qn[i] * eg;
        Ks[i][d] = kk * en;
    }
    __syncthreads();

#pragma unroll
    for (int s = 0; s < 3; s++) {
        int off = (tid * 3 + s) * 4;
        int r = off / 192, c = off - r * 192;
        *(float4*)(blob + OQ + off) = *(const float4*)&Qs[r][c];
    }
    if (tid < 192) {
        float lam = __expf(Ls[15][tid]);
        blob[OLAM + tid] = lam;
#pragma unroll
        for (int j4 = 0; j4 < 4; j4++) {
            float4 v;
            v.x = Ks[j4 * 4 + 0][tid] * lam; v.y = Ks[j4 * 4 + 1][tid] * lam;
            v.z = Ks[j4 * 4 + 2][tid] * lam; v.w = Ks[j4 * 4 + 3][tid] * lam;
            *(float4*)(blob + OC + tid * 20 + j4 * 4) = v;
        }
        blob[OC + tid * 20 + 16] = lam;
        blob[OC + tid * 20 + 17] = 0.f;
        blob[OC + tid * 20 + 18] = 0.f; blob[OC + tid * 20 + 19] = 0.f;
    }
    {
        const int i = tid >> 4, j = tid & 15;
        float m = 0.f, p = 0.f;
#pragma unroll
        for (int d4 = 0; d4 < 48; d4++) {
            float4 w  = *(const float4*)&Ws[i][d4 * 4];
            float4 ka = *(const float4*)&Ks[j][d4 * 4];
            float4 qa = *(const float4*)&Qs[i][d4 * 4];
            m += w.x * ka.x + w.y * ka.y + w.z * ka.z + w.w * ka.w;
            p += qa.x * ka.x + qa.y * ka.y + qa.z * ka.z + qa.w * ka.w;
        }
        Ms[i][j] = (j < i) ? m : 0.f;
        blob[OPL + tid] = (j <= i) ? p : 0.f;
    }
    __syncthreads();

    float y[16], uu[16];
    const bool doY = (tid < 192);
    const bool doU = (tid >= 128);
    const int dcol = tid, ccol = tid - 128;
    if (doY) {
#pragma unroll
        for (int i = 0; i < 16; i++) y[i] = Ws[i][dcol];
#pragma unroll
        for (int i = 1; i < 16; i++)
#pragma unroll
            for (int j = 0; j < i; j++)
                y[i] = fmaf(-Ms[i][j], y[j], y[i]);
    }
    if (doU) {
#pragma unroll
        for (int i = 0; i < 16; i++)
            uu[i] = bs[i] * kvb[(size_t)(t0 + i) * HKV + h * (DNOPE + DV) + DNOPE + ccol];
#pragma unroll
        for (int i = 1; i < 16; i++)
#pragma unroll
            for (int j = 0; j < i; j++)
                uu[i] = fmaf(-Ms[i][j], uu[j], uu[i]);
    }
    if (doY) {
#pragma unroll
        for (int i = 0; i < 16; i++) Xs[i][dcol] = y[i];
    }
    __syncthreads();
#pragma unroll
    for (int s = 0; s < 3; s++) {
        int off = (tid * 3 + s) * 4;
        int r = off / 192, c = off - r * 192;
        *(float4*)(blob + OY + off) = *(const float4*)&Xs[r][c];
    }
    // u' written transposed, straight from registers: [128 cc][16 ti]
    if (doU) {
#pragma unroll
        for (int i4 = 0; i4 < 4; i4++) {
            float4 t;
            t.x = uu[i4 * 4 + 0]; t.y = uu[i4 * 4 + 1];
            t.z = uu[i4 * 4 + 2]; t.w = uu[i4 * 4 + 3];
            *(float4*)(blob + OU + (size_t)ccol * 16 + i4 * 4) = t;
        }
    }
}

// ---------------------------------------------------------------------------
// Phase B — R18 dual-stream version verbatim (best total config, 313.3 µs
// @R3; lag-fold+prep2 measured net −7 µs and is abandoned). 256 blocks x
// 1024 threads, phase-shifted streams A={c0,c0+1} / B={c0+2,c0+3}, triple-
// buffered staging, red32v reductions.
// ---------------------------------------------------------------------------
__global__ __launch_bounds__(1024) void kda_chunk(
    const float* __restrict__ pa, unsigned short* __restrict__ obh,
    unsigned short* __restrict__ obl)
{
    __shared__ float Cb[3][3840];
    __shared__ float Pb[3][256];
    __shared__ float ubs[3][64];    // u' slice [4 cc][16 ti]
    __shared__ float lbs[3][192];
    __shared__ float Ss[784];       // state [4 cc][196]
    __shared__ float us[80];        // u [4 cc][20]

    const int tid = threadIdx.x;
    const int w = tid >> 6, lane = tid & 63;
    const int h = blockIdx.x & 7, cg = blockIdx.x >> 3;   // XCD swizzle
    const int c0 = cg * 4;

    const int ti  = w;              // wave = time row (16 waves)
    const int ccs = lane >> 5;      // stream-local channel (0/1)
    const int dg  = lane & 31;      // 32 d-groups of 6
    const int dbase = dg * 6;

    auto stage = [&](int buf, int n) {
        const float* blob = pa + (size_t)(n * 8 + h) * PABLK;
        if (w < 15) {
            gl_lds16(blob + OC + w * 256 + lane * 4, &Cb[buf][w * 256]);
        } else {
            gl_lds16(blob + OPL + lane * 4, &Pb[buf][0]);
            if (lane < 16)
                gl_lds16(blob + OU + c0 * 16 + lane * 4, &ubs[buf][0]);
            if (lane < 48)
                gl_lds16(blob + OLAM + lane * 4, &lbs[buf][0]);
        }
    };

    auto ldYQ = [&](int n, float2 (&Y)[3], float2 (&Q)[3]) {
        const float* blob = pa + (size_t)(n * 8 + h) * PABLK;
        const float* py_ = blob + OY + ti * 192 + dbase;
        const float* pq_ = blob + OQ + ti * 192 + dbase;
#pragma unroll
        for (int s = 0; s < 3; s++) {
            Y[s] = *(const float2*)(py_ + s * 2);
            Q[s] = *(const float2*)(pq_ + s * 2);
        }
    };

    // P1(stream sbase in {0,2}): z/zq + u-write; returns zq (valid dg>=16)
    auto P1 = [&](int sbase, int bf, float2 (&Yr)[3], float2 (&Qr)[3]) -> float {
        const int r = sbase + ccs;
        const float* Sp = &Ss[r * 196 + dbase];
        float2 s0 = *(const float2*)Sp;
        float2 s1 = *(const float2*)(Sp + 2);
        float2 s2 = *(const float2*)(Sp + 4);
        float ubv = ubs[bf][r * 16 + ti];
        float py0 = Yr[0].x * s0.x, py1 = Yr[0].y * s0.y;
        float pq0 = Qr[0].x * s0.x, pq1 = Qr[0].y * s0.y;
        py0 = fmaf(Yr[1].x, s1.x, py0); py1 = fmaf(Yr[1].y, s1.y, py1);
        pq0 = fmaf(Qr[1].x, s1.x, pq0); pq1 = fmaf(Qr[1].y, s1.y, pq1);
        py0 = fmaf(Yr[2].x, s2.x, py0); py1 = fmaf(Yr[2].y, s2.y, py1);
        pq0 = fmaf(Qr[2].x, s2.x, pq0); pq1 = fmaf(Qr[2].y, s2.y, pq1);
        float zy = red32v(py0 + py1);
        float zq = red32v(pq0 + pq1);
        if (dg == 31) us[r * 20 + ti] = ubv - zy;
        return zq;
    };

    // P2(stream sbase): output (zq + P*u) and S-update.
    auto P2 = [&](int sbase, int bf, int n, float zq) {
        const int r = sbase + ccs;
        float pbvv = Pb[bf][ti * 16 + (dg & 15)];
        float usv  = us[r * 20 + (dg & 15)];
        float acc = (dg <= ti) ? pbvv * usv : 0.f;
        acc = red32v(acc);
        if (dg == 31) {
            float ov = zq + acc;
            if (isnan(ov)) ov = 0.f;
            else if (isinf(ov)) ov = ov > 0.f ? 1e4f : -1e4f;
            size_t oi = (size_t)(n * 16 + ti) * (HH * DV) + h * DV + c0 + r;
            unsigned short hb = f2bf_rn(ov);
            obh[oi] = hb;
            obl[oi] = f2bf_rn(ov - bf2f(hb));
        }
        if (tid < 384) {
            const int d = tid >> 1, c = (tid & 1) + sbase;
            const float4* up4 = (const float4*)&us[c * 20];
            float4 u0 = up4[0], u1 = up4[1], u2v = up4[2], u3 = up4[3];
            float svv = Ss[c * 196 + d];
            const float4* C4 = (const float4*)&Cb[bf][d * 20];
            float4 k0 = C4[0], k1 = C4[1], k2 = C4[2], k3 = C4[3];
            float a0 = lbs[bf][d] * svv, a1 = 0.f;
            a0 = fmaf(k0.x, u0.x,  a0); a1 = fmaf(k0.y, u0.y,  a1);
            a0 = fmaf(k0.z, u0.z,  a0); a1 = fmaf(k0.w, u0.w,  a1);
            a0 = fmaf(k1.x, u1.x,  a0); a1 = fmaf(k1.y, u1.y,  a1);
            a0 = fmaf(k1.z, u1.z,  a0); a1 = fmaf(k1.w, u1.w,  a1);
            a0 = fmaf(k2.x, u2v.x, a0); a1 = fmaf(k2.y, u2v.y, a1);
            a0 = fmaf(k2.z, u2v.z, a0); a1 = fmaf(k2.w, u2v.w, a1);
            a0 = fmaf(k3.x, u3.x,  a0); a1 = fmaf(k3.y, u3.y,  a1);
            a0 = fmaf(k3.z, u3.z,  a0); a1 = fmaf(k3.w, u3.w,  a1);
            Ss[c * 196 + d] = a0 + a1;
        }
    };

#define SEG_BAR asm volatile("s_waitcnt lgkmcnt(0)\n\ts_barrier" ::: "memory")

    float zqA, zqB;
    float2 Ya[3], Qa[3], Yb[3], Qb[3];

    // prologue
    for (int idx = tid; idx < 784; idx += 1024) Ss[idx] = 0.f;
    stage(0, 0);
    stage(1, 1);
    asm volatile("" ::: "memory");
    ldYQ(0, Ya, Qa);
    asm volatile("s_waitcnt vmcnt(0) lgkmcnt(0)\n\ts_barrier" ::: "memory");
    zqA = P1(0, 0, Ya, Qa);          // seg 0: A.P1(0)
    SEG_BAR;

    int bf = 0;
    for (int n = 0; n < 62; n += 2) {
        int bf1 = bf + 1; if (bf1 >= 3) bf1 -= 3;
        int bf2 = bf + 2; if (bf2 >= 3) bf2 -= 3;
        // ODD(n): stage(n+2), ldYQ(n+1); B.P1(n) ; A.P2(n)
        stage(bf2, n + 2);
        asm volatile("" ::: "memory");
        ldYQ(n + 1, Yb, Qb);
        zqB = P1(2, bf, Ya, Qa);
        P2(0, bf, n, zqA);
        SEG_BAR;
        // EVEN(n): A.P1(n+1) ; B.P2(n)
        zqA = P1(0, bf1, Yb, Qb);
        P2(2, bf, n, zqB);
        SEG_BAR;
        // ODD(n+1): stage(n+3), ldYQ(n+2); B.P1(n+1) ; A.P2(n+1)
        stage(bf, n + 3);
        asm volatile("" ::: "memory");
        ldYQ(n + 2, Ya, Qa);
        zqB = P1(2, bf1, Yb, Qb);
        P2(0, bf1, n + 1, zqA);
        SEG_BAR;
        // EVEN(n+1): A.P1(n+2) ; B.P2(n+1)
        zqA = P1(0, bf2, Ya, Qa);
        P2(2, bf1, n + 1, zqB);
        SEG_BAR;
        bf = bf2;
    }
    // bf = 62%3 = 2; Ya holds YQ(62); zqA = A.P1(62)
    {
        int bf1 = bf + 1; if (bf1 >= 3) bf1 -= 3;   // 63%3
        // ODD(62): ldYQ(63); B.P1(62) ; A.P2(62)
        ldYQ(63, Yb, Qb);
        zqB = P1(2, bf, Ya, Qa);
        P2(0, bf, 62, zqA);
        SEG_BAR;
        // EVEN(62): A.P1(63) ; B.P2(62)
        zqA = P1(0, bf1, Yb, Qb);
        P2(2, bf, 62, zqB);
        SEG_BAR;
        // ODD(63): B.P1(63) ; A.P2(63)
        zqB = P1(2, bf1, Yb, Qb);
        P2(0, bf1, 63, zqA);
        SEG_BAR;
        // seg 128: B.P2(63)
        P2(2, bf1, 63, zqB);
    }
#undef SEG_BAR
}

// ---------------------------------------------------------------------------
extern "C" void kernel_launch(void* const* d_in, const int* in_sizes, int n_in,
                              void* d_out, int out_size, void* d_ws, size_t ws_size,
                              hipStream_t stream)
{
    const float* x         = (const float*)d_in[0];
    // d_in[1] = cos, d_in[2] = sin : unused by the reference
    const float* wq_a      = (const float*)d_in[3];
    const float* q_norm_w  = (const float*)d_in[4];
    const float* wq_b      = (const float*)d_in[5];
    const float* wkv_a     = (const float*)d_in[6];
    const float* kv_norm_w = (const float*)d_in[7];
    const float* wkv_b     = (const float*)d_in[8];
    const float* wg_w      = (const float*)d_in[9];
    const float* wg_b      = (const float*)d_in[10];
    const float* wb        = (const float*)d_in[11];
    const float* wo        = (const float*)d_in[12];
    float* out = (float*)d_out;

    float* ws = (float*)d_ws;
    float* xq     = ws;                        // T x 768 (f32, gemm1 out)
    float* kv_all = xq     + TT * QLR;         // T x 576
    float* agraw  = kv_all + TT * (KVLR + DROPE); // T x 1536
    float* qnraw  = agraw  + TT * HDK;         // T x 1536
    float* kvb    = qnraw  + TT * HDK;         // T x 2048
    float* spare  = kvb    + TT * HKV;         // (was la_h/q_h/k_h/betab)
    float* pa     = spare  + 3 * TT * HDK + TT * HH;  // 512 x PABLK (25.6 MB)
    float* tail   = pa     + 512 * PABLK;

    unsigned short* wo_h  = (unsigned short*)tail;          // 1024*1024
    unsigned short* wo_l  = wo_h  + 1048576;
    unsigned short* xh    = wo_l  + 1048576;                // 1024*1024
    unsigned short* xl    = xh    + 1048576;
    unsigned short* xqh   = xl    + 1048576;                // 1024*768
    unsigned short* xql   = xqh   + 786432;
    unsigned short* kvnh  = xql   + 786432;                 // 1024*512
    unsigned short* kvnl  = kvnh  + 524288;

    unsigned short* wqa_h  = (unsigned short*)pa;           // 768n x 1024k
    unsigned short* wqa_l  = wqa_h  + 786432;
    unsigned short* wkva_h = wqa_l  + 786432;               // 576n x 1024k
    unsigned short* wkva_l = wkva_h + 589824;
    unsigned short* wgw_h  = wkva_l + 589824;               // 1536n x 1024k
    unsigned short* wgw_l  = wgw_h  + 1572864;
    unsigned short* wqb_h  = wgw_l  + 1572864;              // 1536n x 768k
    unsigned short* wqb_l  = wqb_h  + 1179648;
    unsigned short* wkvb_h = wqb_l  + 1179648;              // 2048n x 512k
    unsigned short* wkvb_l = wkvb_h + 1048576;

    unsigned short* obh = (unsigned short*)spare;           // 1024*1024
    unsigned short* obl = obh + 1048576;

    dim3 blk(256);

    wconv<<<dim3(192 + 144 + 384), blk, 0, stream>>>(
        wq_a, wqa_h, wqa_l, DIM, QLR, 192,
        wkv_a, wkva_h, wkva_l, DIM, KVLR + DROPE, 144,
        wg_w, wgw_h, wgw_l, DIM, HDK, 384);
    wconv<<<dim3(288 + 256 + 256), blk, 0, stream>>>(
        wq_b, wqb_h, wqb_l, QLR, HDK, 288,
        wkv_b, wkvb_h, wkvb_l, KVLR, HKV, 256,
        wo, wo_h, wo_l, DIM, DIM, 256);

    aconv<<<dim3(TT * DIM / (256 * 8)), blk, 0, stream>>>(x, xh, xl);

    gemm_bt<<<dim3(12 + 9 + 24, 16), dim3(128), 0, stream>>>(
        xh, xl, wqa_h, wqa_l, xq, DIM, QLR, 12,
        xh, xl, wkva_h, wkva_l, kv_all, DIM, KVLR + DROPE, 9,
        xh, xl, wgw_h, wgw_l, agraw, DIM, HDK, 24);

    rmsnorm_bf2<<<dim3(2 * TT), blk, 0, stream>>>(
        xq, q_norm_w, xqh, xql,
        kv_all, kv_norm_w, kvnh, kvnl);

    gemm_bt<<<dim3(24 + 32, 16), dim3(128), 0, stream>>>(
        xqh, xql, wqb_h, wqb_l, qnraw, QLR, HDK, 24,
        kvnh, kvnl, wkvb_h, wkvb_l, kvb, KVLR, HKV, 32,
        xh, xl, wqa_h, wqa_l, xq, DIM, QLR, 0);

    chunk_prep<<<512, blk, 0, stream>>>(
        qnraw, agraw, wg_b, kvb, kv_all, x, wb, pa);
    kda_chunk<<<256, dim3(1024), 0, stream>>>(pa, obh, obl);

    gemm_bt<<<dim3(16, 16), dim3(128), 0, stream>>>(
        obh, obl, wo_h, wo_l, out, DIM, DIM, 16,
        xh, xl, wqa_h, wqa_l, xq, DIM, QLR, 0,
        xh, xl, wqa_h, wqa_l, xq, DIM, QLR, 0);
}